// Round 5
// baseline (267.681 us; speedup 1.0000x reference)
//
#include <hip/hip_runtime.h>

#define NN 8192
#define EE 65536

// ---------------------------------------------------------------------------
// k_pre: zero cnt[8192] + pack Wf1 = concat(nn1_w, nn1_b, root1) [640x48]
//        and Wf2 = concat(nn2_w, nn2_b, root2) [480x32] (source order already
//        matches the fused-K layout). 212*256 = 8192 + 30720 + 15360 threads.
// ---------------------------------------------------------------------------
__global__ __launch_bounds__(256) void k_pre(const float* __restrict__ w1,
                                             const float* __restrict__ b1,
                                             const float* __restrict__ r1,
                                             const float* __restrict__ w2,
                                             const float* __restrict__ b2,
                                             const float* __restrict__ r2,
                                             float* __restrict__ Wf1,
                                             float* __restrict__ Wf2,
                                             int* __restrict__ cnt) {
    int t = blockIdx.x * 256 + threadIdx.x;
    if (t < 8192) { cnt[t] = 0; return; }
    t -= 8192;
    if (t < 30720) {
        float v;
        if (t < 24576)      v = w1[t];
        else if (t < 27648) v = b1[t - 24576];
        else                v = r1[t - 27648];
        Wf1[t] = v;
        return;
    }
    t -= 30720;
    float v;
    if (t < 12288)      v = w2[t];
    else if (t < 13824) v = b2[t - 12288];
    else                v = r2[t - 13824];
    Wf2[t] = v;
}

__global__ __launch_bounds__(256) void k_hist(const int* __restrict__ ei,
                                              int* __restrict__ cnt) {
    int e = blockIdx.x * 256 + threadIdx.x;
    atomicAdd(&cnt[ei[EE + e]], 1);
}

// Single-block scan of 8192 degree counts -> row_ptr[8193] and cursor copy.
__global__ __launch_bounds__(1024) void k_scan(const int* __restrict__ cnt,
                                               int* __restrict__ row_ptr,
                                               int* __restrict__ cursor) {
    __shared__ int sd[1024];
    const int t = threadIdx.x;
    const int base = t * 8;
    int v[8];
    int s = 0;
#pragma unroll
    for (int j = 0; j < 8; j++) { v[j] = cnt[base + j]; s += v[j]; }
    sd[t] = s;
    __syncthreads();
    for (int off = 1; off < 1024; off <<= 1) {
        int a = sd[t];
        int b = (t >= off) ? sd[t - off] : 0;
        __syncthreads();
        sd[t] = a + b;
        __syncthreads();
    }
    int run = sd[t] - s;  // exclusive prefix
#pragma unroll
    for (int j = 0; j < 8; j++) {
        row_ptr[base + j] = run;
        cursor[base + j] = run;
        run += v[j];
    }
    if (t == 1023) row_ptr[8192] = run;
}

// cs2[slot] = (e, src): one 8B store; kills the ei[e] chain level in gathers.
__global__ __launch_bounds__(256) void k_scatter(const int* __restrict__ ei,
                                                 int* __restrict__ cursor,
                                                 int2* __restrict__ cs2) {
    int e = blockIdx.x * 256 + threadIdx.x;
    int s = ei[e];
    int d = ei[EE + e];
    int slot = atomicAdd(&cursor[d], 1);
    cs2[slot] = make_int2(e, s);
}

// ---------------------------------------------------------------------------
// k_y1: one wave per dst node, lane = input channel (64). Unrolled-by-4 edge
// loop: 4 independent x-row gathers in flight. Z1 row = [y0..y8 (576), x_d].
// 2048 blocks x 256 = 8192 waves = 32/CU.
// ---------------------------------------------------------------------------
__global__ __launch_bounds__(256) void k_y1(const int2* __restrict__ cs2,
                                            const float* __restrict__ ea,
                                            const float* __restrict__ x,
                                            const int* __restrict__ row_ptr,
                                            float* __restrict__ Z1) {
    const int lane = threadIdx.x & 63;
    const int d = blockIdx.x * 4 + (threadIdx.x >> 6);
    float y[9];
#pragma unroll
    for (int f = 0; f < 9; f++) y[f] = 0.f;
    const int rp0 = row_ptr[d], rp1 = row_ptr[d + 1];
    int idx = rp0;
    for (; idx + 4 <= rp1; idx += 4) {
        int2 p0 = cs2[idx], p1 = cs2[idx + 1], p2 = cs2[idx + 2], p3 = cs2[idx + 3];
        float x0 = x[(size_t)p0.y * 64 + lane];
        float x1 = x[(size_t)p1.y * 64 + lane];
        float x2 = x[(size_t)p2.y * 64 + lane];
        float x3 = x[(size_t)p3.y * 64 + lane];
        float4 a00 = *(const float4*)(ea + (size_t)p0.x * 8);
        float4 a01 = *(const float4*)(ea + (size_t)p0.x * 8 + 4);
        float4 a10 = *(const float4*)(ea + (size_t)p1.x * 8);
        float4 a11 = *(const float4*)(ea + (size_t)p1.x * 8 + 4);
        float4 a20 = *(const float4*)(ea + (size_t)p2.x * 8);
        float4 a21 = *(const float4*)(ea + (size_t)p2.x * 8 + 4);
        float4 a30 = *(const float4*)(ea + (size_t)p3.x * 8);
        float4 a31 = *(const float4*)(ea + (size_t)p3.x * 8 + 4);
        y[0] += a00.x * x0 + a10.x * x1 + a20.x * x2 + a30.x * x3;
        y[1] += a00.y * x0 + a10.y * x1 + a20.y * x2 + a30.y * x3;
        y[2] += a00.z * x0 + a10.z * x1 + a20.z * x2 + a30.z * x3;
        y[3] += a00.w * x0 + a10.w * x1 + a20.w * x2 + a30.w * x3;
        y[4] += a01.x * x0 + a11.x * x1 + a21.x * x2 + a31.x * x3;
        y[5] += a01.y * x0 + a11.y * x1 + a21.y * x2 + a31.y * x3;
        y[6] += a01.z * x0 + a11.z * x1 + a21.z * x2 + a31.z * x3;
        y[7] += a01.w * x0 + a11.w * x1 + a21.w * x2 + a31.w * x3;
        y[8] += x0 + x1 + x2 + x3;
    }
    for (; idx < rp1; idx++) {
        int2 p = cs2[idx];
        float xv = x[(size_t)p.y * 64 + lane];
        float4 a0 = *(const float4*)(ea + (size_t)p.x * 8);
        float4 a1 = *(const float4*)(ea + (size_t)p.x * 8 + 4);
        y[0] += a0.x * xv; y[1] += a0.y * xv; y[2] += a0.z * xv; y[3] += a0.w * xv;
        y[4] += a1.x * xv; y[5] += a1.y * xv; y[6] += a1.z * xv; y[7] += a1.w * xv;
        y[8] += xv;
    }
    float* zr = Z1 + (size_t)d * 640;
#pragma unroll
    for (int f = 0; f < 9; f++) zr[f * 64 + lane] = y[f];
    zr[576 + lane] = x[(size_t)d * 64 + lane];
}

// ---------------------------------------------------------------------------
// k_g1: h1 = relu(Z1[8192x640] @ Wf1[640x48] + bias1).
// Sync-free register GEMM: thread = (node-pair, col-quad). 4096*12 = 49152
// threads, 384 blocks x 128. Z float4 loads broadcast across the 12 lanes
// sharing a node; W quads (192 B/k) shared wave-wide via L1. No LDS.
// ---------------------------------------------------------------------------
__global__ __launch_bounds__(128) void k_g1(const float* __restrict__ Z1,
                                            const float* __restrict__ Wf1,
                                            const float* __restrict__ bias1,
                                            float* __restrict__ h1) {
    const int gid = blockIdx.x * 128 + threadIdx.x;
    const int n2 = gid / 12, c4 = gid - n2 * 12;
    const int n0 = n2 * 2;
    const float* z0 = Z1 + (size_t)n0 * 640;
    const float* z1 = z0 + 640;
    const float* wp = Wf1 + c4 * 4;
    float4 acc0 = make_float4(0.f, 0.f, 0.f, 0.f);
    float4 acc1 = make_float4(0.f, 0.f, 0.f, 0.f);
#pragma unroll 4
    for (int k = 0; k < 640; k += 4) {
        float4 a0 = *(const float4*)(z0 + k);
        float4 a1 = *(const float4*)(z1 + k);
        float4 w0 = *(const float4*)(wp + (size_t)(k + 0) * 48);
        float4 w1 = *(const float4*)(wp + (size_t)(k + 1) * 48);
        float4 w2 = *(const float4*)(wp + (size_t)(k + 2) * 48);
        float4 w3 = *(const float4*)(wp + (size_t)(k + 3) * 48);
        acc0.x += a0.x * w0.x + a0.y * w1.x + a0.z * w2.x + a0.w * w3.x;
        acc0.y += a0.x * w0.y + a0.y * w1.y + a0.z * w2.y + a0.w * w3.y;
        acc0.z += a0.x * w0.z + a0.y * w1.z + a0.z * w2.z + a0.w * w3.z;
        acc0.w += a0.x * w0.w + a0.y * w1.w + a0.z * w2.w + a0.w * w3.w;
        acc1.x += a1.x * w0.x + a1.y * w1.x + a1.z * w2.x + a1.w * w3.x;
        acc1.y += a1.x * w0.y + a1.y * w1.y + a1.z * w2.y + a1.w * w3.y;
        acc1.z += a1.x * w0.z + a1.y * w1.z + a1.z * w2.z + a1.w * w3.z;
        acc1.w += a1.x * w0.w + a1.y * w1.w + a1.z * w2.w + a1.w * w3.w;
    }
    float4 b = *(const float4*)(bias1 + c4 * 4);
    float4 o0, o1;
    o0.x = fmaxf(acc0.x + b.x, 0.f); o0.y = fmaxf(acc0.y + b.y, 0.f);
    o0.z = fmaxf(acc0.z + b.z, 0.f); o0.w = fmaxf(acc0.w + b.w, 0.f);
    o1.x = fmaxf(acc1.x + b.x, 0.f); o1.y = fmaxf(acc1.y + b.y, 0.f);
    o1.z = fmaxf(acc1.z + b.z, 0.f); o1.w = fmaxf(acc1.w + b.w, 0.f);
    *(float4*)(h1 + (size_t)n0 * 48 + c4 * 4) = o0;
    *(float4*)(h1 + (size_t)(n0 + 1) * 48 + c4 * 4) = o1;
}

// ---------------------------------------------------------------------------
// k_y2: one wave per dst, lanes 0..47 = h1 channel, unrolled-by-4.
// Z2 row = [y0..y8 (432), h1_d (48)].
// ---------------------------------------------------------------------------
__global__ __launch_bounds__(256) void k_y2(const int2* __restrict__ cs2,
                                            const float* __restrict__ ea,
                                            const float* __restrict__ h1,
                                            const int* __restrict__ row_ptr,
                                            float* __restrict__ Z2) {
    const int lane = threadIdx.x & 63;
    const int d = blockIdx.x * 4 + (threadIdx.x >> 6);
    if (lane >= 48) return;
    float y[9];
#pragma unroll
    for (int f = 0; f < 9; f++) y[f] = 0.f;
    const int rp0 = row_ptr[d], rp1 = row_ptr[d + 1];
    int idx = rp0;
    for (; idx + 4 <= rp1; idx += 4) {
        int2 p0 = cs2[idx], p1 = cs2[idx + 1], p2 = cs2[idx + 2], p3 = cs2[idx + 3];
        float x0 = h1[(size_t)p0.y * 48 + lane];
        float x1 = h1[(size_t)p1.y * 48 + lane];
        float x2 = h1[(size_t)p2.y * 48 + lane];
        float x3 = h1[(size_t)p3.y * 48 + lane];
        float4 a00 = *(const float4*)(ea + (size_t)p0.x * 8);
        float4 a01 = *(const float4*)(ea + (size_t)p0.x * 8 + 4);
        float4 a10 = *(const float4*)(ea + (size_t)p1.x * 8);
        float4 a11 = *(const float4*)(ea + (size_t)p1.x * 8 + 4);
        float4 a20 = *(const float4*)(ea + (size_t)p2.x * 8);
        float4 a21 = *(const float4*)(ea + (size_t)p2.x * 8 + 4);
        float4 a30 = *(const float4*)(ea + (size_t)p3.x * 8);
        float4 a31 = *(const float4*)(ea + (size_t)p3.x * 8 + 4);
        y[0] += a00.x * x0 + a10.x * x1 + a20.x * x2 + a30.x * x3;
        y[1] += a00.y * x0 + a10.y * x1 + a20.y * x2 + a30.y * x3;
        y[2] += a00.z * x0 + a10.z * x1 + a20.z * x2 + a30.z * x3;
        y[3] += a00.w * x0 + a10.w * x1 + a20.w * x2 + a30.w * x3;
        y[4] += a01.x * x0 + a11.x * x1 + a21.x * x2 + a31.x * x3;
        y[5] += a01.y * x0 + a11.y * x1 + a21.y * x2 + a31.y * x3;
        y[6] += a01.z * x0 + a11.z * x1 + a21.z * x2 + a31.z * x3;
        y[7] += a01.w * x0 + a11.w * x1 + a21.w * x2 + a31.w * x3;
        y[8] += x0 + x1 + x2 + x3;
    }
    for (; idx < rp1; idx++) {
        int2 p = cs2[idx];
        float xv = h1[(size_t)p.y * 48 + lane];
        float4 a0 = *(const float4*)(ea + (size_t)p.x * 8);
        float4 a1 = *(const float4*)(ea + (size_t)p.x * 8 + 4);
        y[0] += a0.x * xv; y[1] += a0.y * xv; y[2] += a0.z * xv; y[3] += a0.w * xv;
        y[4] += a1.x * xv; y[5] += a1.y * xv; y[6] += a1.z * xv; y[7] += a1.w * xv;
        y[8] += xv;
    }
    float* zr = Z2 + (size_t)d * 480;
#pragma unroll
    for (int f = 0; f < 9; f++) zr[f * 48 + lane] = y[f];
    zr[432 + lane] = h1[(size_t)d * 48 + lane];
}

// ---------------------------------------------------------------------------
// k_g2: h2 = relu(Z2[8192x480] @ Wf2[480x32] + bias2). Same sync-free
// structure: thread = (node-pair, col-quad of 8). 4096*8 = 32768 threads,
// 256 blocks x 128.
// ---------------------------------------------------------------------------
__global__ __launch_bounds__(128) void k_g2(const float* __restrict__ Z2,
                                            const float* __restrict__ Wf2,
                                            const float* __restrict__ bias2,
                                            float* __restrict__ h2) {
    const int gid = blockIdx.x * 128 + threadIdx.x;
    const int n2 = gid >> 3, c4 = gid & 7;
    const int n0 = n2 * 2;
    const float* z0 = Z2 + (size_t)n0 * 480;
    const float* z1 = z0 + 480;
    const float* wp = Wf2 + c4 * 4;
    float4 acc0 = make_float4(0.f, 0.f, 0.f, 0.f);
    float4 acc1 = make_float4(0.f, 0.f, 0.f, 0.f);
#pragma unroll 4
    for (int k = 0; k < 480; k += 4) {
        float4 a0 = *(const float4*)(z0 + k);
        float4 a1 = *(const float4*)(z1 + k);
        float4 w0 = *(const float4*)(wp + (size_t)(k + 0) * 32);
        float4 w1 = *(const float4*)(wp + (size_t)(k + 1) * 32);
        float4 w2 = *(const float4*)(wp + (size_t)(k + 2) * 32);
        float4 w3 = *(const float4*)(wp + (size_t)(k + 3) * 32);
        acc0.x += a0.x * w0.x + a0.y * w1.x + a0.z * w2.x + a0.w * w3.x;
        acc0.y += a0.x * w0.y + a0.y * w1.y + a0.z * w2.y + a0.w * w3.y;
        acc0.z += a0.x * w0.z + a0.y * w1.z + a0.z * w2.z + a0.w * w3.z;
        acc0.w += a0.x * w0.w + a0.y * w1.w + a0.z * w2.w + a0.w * w3.w;
        acc1.x += a1.x * w0.x + a1.y * w1.x + a1.z * w2.x + a1.w * w3.x;
        acc1.y += a1.x * w0.y + a1.y * w1.y + a1.z * w2.y + a1.w * w3.y;
        acc1.z += a1.x * w0.z + a1.y * w1.z + a1.z * w2.z + a1.w * w3.z;
        acc1.w += a1.x * w0.w + a1.y * w1.w + a1.z * w2.w + a1.w * w3.w;
    }
    float4 b = *(const float4*)(bias2 + c4 * 4);
    float4 o0, o1;
    o0.x = fmaxf(acc0.x + b.x, 0.f); o0.y = fmaxf(acc0.y + b.y, 0.f);
    o0.z = fmaxf(acc0.z + b.z, 0.f); o0.w = fmaxf(acc0.w + b.w, 0.f);
    o1.x = fmaxf(acc1.x + b.x, 0.f); o1.y = fmaxf(acc1.y + b.y, 0.f);
    o1.z = fmaxf(acc1.z + b.z, 0.f); o1.w = fmaxf(acc1.w + b.w, 0.f);
    *(float4*)(h2 + (size_t)n0 * 32 + c4 * 4) = o0;
    *(float4*)(h2 + (size_t)(n0 + 1) * 32 + c4 * 4) = o1;
}

// ---------------------------------------------------------------------------
// k_head: thread = (node, out-quad of 8): 16 mu + 16 ls outputs.
// hcat[d] = head(h2[d]) * dinv[d] (pre-scaled for GCN gather);
// out init = self-loop (deg^-1) + bias; dinv stored. Sync-free, 65536 thr.
// ---------------------------------------------------------------------------
__global__ __launch_bounds__(256) void k_head(const float* __restrict__ h2,
                                              const float* __restrict__ mu_w,
                                              const float* __restrict__ mu_b,
                                              const float* __restrict__ ls_w,
                                              const float* __restrict__ ls_b,
                                              const int* __restrict__ row_ptr,
                                              float* __restrict__ hcat,
                                              float* __restrict__ dinv,
                                              float* __restrict__ out) {
    const int gid = blockIdx.x * 256 + threadIdx.x;
    const int n = gid >> 3, oq = gid & 7;
    const int q = oq >> 2;          // 0 = mu, 1 = ls
    const int j0 = (oq & 3) * 4;    // output col base
    const float* wh = (q ? ls_w : mu_w) + j0;
    const float* bh = q ? ls_b : mu_b;
    const float* hr = h2 + (size_t)n * 32;
    float4 acc = make_float4(0.f, 0.f, 0.f, 0.f);
#pragma unroll
    for (int i4 = 0; i4 < 8; i4++) {
        float4 v = *(const float4*)(hr + i4 * 4);
        float4 w0 = *(const float4*)(wh + (size_t)(i4 * 4 + 0) * 16);
        float4 w1 = *(const float4*)(wh + (size_t)(i4 * 4 + 1) * 16);
        float4 w2 = *(const float4*)(wh + (size_t)(i4 * 4 + 2) * 16);
        float4 w3 = *(const float4*)(wh + (size_t)(i4 * 4 + 3) * 16);
        acc.x += v.x * w0.x + v.y * w1.x + v.z * w2.x + v.w * w3.x;
        acc.y += v.x * w0.y + v.y * w1.y + v.z * w2.y + v.w * w3.y;
        acc.z += v.x * w0.z + v.y * w1.z + v.z * w2.z + v.w * w3.z;
        acc.w += v.x * w0.w + v.y * w1.w + v.z * w2.w + v.w * w3.w;
    }
    const int deg = row_ptr[n + 1] - row_ptr[n] + 1;
    const float invd = 1.f / (float)deg;
    const float di = rsqrtf((float)deg);
    if (oq == 0) dinv[n] = di;
    float4 hv, ov;
    hv.x = acc.x * di; hv.y = acc.y * di; hv.z = acc.z * di; hv.w = acc.w * di;
    float4 b = *(const float4*)(bh + j0);
    ov.x = acc.x * invd + b.x; ov.y = acc.y * invd + b.y;
    ov.z = acc.z * invd + b.z; ov.w = acc.w * invd + b.w;
    *(float4*)(hcat + (size_t)n * 32 + q * 16 + j0) = hv;
    *(float4*)(out + (q ? (size_t)NN * 16 : (size_t)0) + (size_t)n * 16 + j0) = ov;
}

// ---------------------------------------------------------------------------
// k_gcn: half-wave (32 lanes) per dst: out[d] += dinv[d] * sum_s hcat[s]
// (hcat pre-scaled by dinv[s]). Unrolled by 4.
// ---------------------------------------------------------------------------
__global__ __launch_bounds__(256) void k_gcn(const int2* __restrict__ cs2,
                                             const int* __restrict__ row_ptr,
                                             const float* __restrict__ hcat,
                                             const float* __restrict__ dinv,
                                             float* __restrict__ out) {
    const int t = threadIdx.x;
    const int lane32 = t & 31;
    const int d = blockIdx.x * 8 + (t >> 5);
    float acc = 0.f;
    const int rp0 = row_ptr[d], rp1 = row_ptr[d + 1];
    int idx = rp0;
    for (; idx + 4 <= rp1; idx += 4) {
        int2 p0 = cs2[idx], p1 = cs2[idx + 1], p2 = cs2[idx + 2], p3 = cs2[idx + 3];
        float v0 = hcat[(size_t)p0.y * 32 + lane32];
        float v1 = hcat[(size_t)p1.y * 32 + lane32];
        float v2 = hcat[(size_t)p2.y * 32 + lane32];
        float v3 = hcat[(size_t)p3.y * 32 + lane32];
        acc += (v0 + v1) + (v2 + v3);
    }
    for (; idx < rp1; idx++) {
        int2 p = cs2[idx];
        acc += hcat[(size_t)p.y * 32 + lane32];
    }
    acc *= dinv[d];
    const int col = lane32 & 15;
    const size_t addr = (lane32 < 16) ? ((size_t)d * 16 + col)
                                      : ((size_t)NN * 16 + (size_t)d * 16 + col);
    out[addr] += acc;
}

extern "C" void kernel_launch(void* const* d_in, const int* in_sizes, int n_in,
                              void* d_out, int out_size, void* d_ws, size_t ws_size,
                              hipStream_t stream) {
    const float* x     = (const float*)d_in[0];
    const int*   ei    = (const int*)d_in[1];
    const float* ea    = (const float*)d_in[2];
    const float* nn1_w = (const float*)d_in[3];
    const float* nn1_b = (const float*)d_in[4];
    const float* root1 = (const float*)d_in[5];
    const float* bias1 = (const float*)d_in[6];
    const float* nn2_w = (const float*)d_in[7];
    const float* nn2_b = (const float*)d_in[8];
    const float* root2 = (const float*)d_in[9];
    const float* bias2 = (const float*)d_in[10];
    const float* mu_w  = (const float*)d_in[11];
    const float* mu_b  = (const float*)d_in[12];
    const float* ls_w  = (const float*)d_in[13];
    const float* ls_b  = (const float*)d_in[14];
    float* out = (float*)d_out;

    // Workspace layout (float units; every segment start divisible by 4)
    float* W       = (float*)d_ws;
    float* Wf1     = W;                        //    30,720
    float* Wf2     = Wf1 + 30720;              //    15,360
    int*   cnt     = (int*)(Wf2 + 15360);      //     8,192
    int*   row_ptr = cnt + 8192;               //     8,196
    int*   cursor  = row_ptr + 8196;           //     8,192
    int2*  cs2     = (int2*)(cursor + 8192);   //    65,536 int2 = 131,072
    float* Z1      = (float*)(cs2 + 65536);    // 5,242,880
    float* Z2      = Z1 + 5242880;             // 3,932,160
    float* h1      = Z2 + 3932160;             //   393,216
    float* h2      = h1 + 393216;              //   262,144
    float* hcat    = h2 + 262144;              //   262,144
    float* dinv    = hcat + 262144;            //     8,192
    // total ~41 MB

    k_pre<<<dim3(212), dim3(256), 0, stream>>>(nn1_w, nn1_b, root1,
                                               nn2_w, nn2_b, root2,
                                               Wf1, Wf2, cnt);
    k_hist<<<dim3(256), dim3(256), 0, stream>>>(ei, cnt);
    k_scan<<<dim3(1), dim3(1024), 0, stream>>>(cnt, row_ptr, cursor);
    k_scatter<<<dim3(256), dim3(256), 0, stream>>>(ei, cursor, cs2);
    k_y1<<<dim3(2048), dim3(256), 0, stream>>>(cs2, ea, x, row_ptr, Z1);
    k_g1<<<dim3(384), dim3(128), 0, stream>>>(Z1, Wf1, bias1, h1);
    k_y2<<<dim3(2048), dim3(256), 0, stream>>>(cs2, ea, h1, row_ptr, Z2);
    k_g2<<<dim3(256), dim3(128), 0, stream>>>(Z2, Wf2, bias2, h2);
    k_head<<<dim3(256), dim3(256), 0, stream>>>(h2, mu_w, mu_b, ls_w, ls_b,
                                                row_ptr, hcat, dinv, out);
    k_gcn<<<dim3(1024), dim3(256), 0, stream>>>(cs2, row_ptr, hcat, dinv, out);
}

// Round 6
// 221.422 us; speedup vs baseline: 1.2089x; 1.2089x over previous
//
#include <hip/hip_runtime.h>

#define NN 8192
#define EE 65536

// ---------------------------------------------------------------------------
// k_hist: degree histogram over dst.
// ---------------------------------------------------------------------------
__global__ __launch_bounds__(256) void k_hist(const int* __restrict__ ei,
                                              int* __restrict__ cnt) {
    int e = blockIdx.x * 256 + threadIdx.x;
    atomicAdd(&cnt[ei[EE + e]], 1);
}

// Single-block scan of 8192 degree counts -> row_ptr[8193] and cursor copy.
__global__ __launch_bounds__(1024) void k_scan(const int* __restrict__ cnt,
                                               int* __restrict__ row_ptr,
                                               int* __restrict__ cursor) {
    __shared__ int sd[1024];
    const int t = threadIdx.x;
    const int base = t * 8;
    int v[8];
    int s = 0;
#pragma unroll
    for (int j = 0; j < 8; j++) { v[j] = cnt[base + j]; s += v[j]; }
    sd[t] = s;
    __syncthreads();
    for (int off = 1; off < 1024; off <<= 1) {
        int a = sd[t];
        int b = (t >= off) ? sd[t - off] : 0;
        __syncthreads();
        sd[t] = a + b;
        __syncthreads();
    }
    int run = sd[t] - s;  // exclusive prefix
#pragma unroll
    for (int j = 0; j < 8; j++) {
        row_ptr[base + j] = run;
        cursor[base + j] = run;
        run += v[j];
    }
    if (t == 1023) row_ptr[8192] = run;
}

// ---------------------------------------------------------------------------
// k_scatpack: CSR scatter (cs2[slot] = (e, src)) for t < 65536, plus packing
// Wf1 = concat(nn1_w, nn1_b, root1) [640x48] and Wf2 [480x32] for the rest.
// grid 436*256 = 65536 + 30720 + 15360.
// ---------------------------------------------------------------------------
__global__ __launch_bounds__(256) void k_scatpack(const int* __restrict__ ei,
                                                  int* __restrict__ cursor,
                                                  int2* __restrict__ cs2,
                                                  const float* __restrict__ w1,
                                                  const float* __restrict__ b1,
                                                  const float* __restrict__ r1,
                                                  const float* __restrict__ w2,
                                                  const float* __restrict__ b2,
                                                  const float* __restrict__ r2,
                                                  float* __restrict__ Wf1,
                                                  float* __restrict__ Wf2) {
    int t = blockIdx.x * 256 + threadIdx.x;
    if (t < EE) {
        int s = ei[t];
        int d = ei[EE + t];
        int slot = atomicAdd(&cursor[d], 1);
        cs2[slot] = make_int2(t, s);
        return;
    }
    t -= EE;
    if (t < 30720) {
        float v;
        if (t < 24576)      v = w1[t];
        else if (t < 27648) v = b1[t - 24576];
        else                v = r1[t - 27648];
        Wf1[t] = v;
        return;
    }
    t -= 30720;
    float v;
    if (t < 12288)      v = w2[t];
    else if (t < 13824) v = b2[t - 12288];
    else                v = r2[t - 13824];
    Wf2[t] = v;
}

// ---------------------------------------------------------------------------
// k_y1: one wave per dst node, lane = input channel (64). Unrolled-by-4 edge
// loop. Z1 row = [y0..y8 (576), x_d (64)] (node-major; transposed by k_t).
// ---------------------------------------------------------------------------
__global__ __launch_bounds__(256) void k_y1(const int2* __restrict__ cs2,
                                            const float* __restrict__ ea,
                                            const float* __restrict__ x,
                                            const int* __restrict__ row_ptr,
                                            float* __restrict__ Z1) {
    const int lane = threadIdx.x & 63;
    const int d = blockIdx.x * 4 + (threadIdx.x >> 6);
    float y[9];
#pragma unroll
    for (int f = 0; f < 9; f++) y[f] = 0.f;
    const int rp0 = row_ptr[d], rp1 = row_ptr[d + 1];
    int idx = rp0;
    for (; idx + 4 <= rp1; idx += 4) {
        int2 p0 = cs2[idx], p1 = cs2[idx + 1], p2 = cs2[idx + 2], p3 = cs2[idx + 3];
        float x0 = x[(size_t)p0.y * 64 + lane];
        float x1 = x[(size_t)p1.y * 64 + lane];
        float x2 = x[(size_t)p2.y * 64 + lane];
        float x3 = x[(size_t)p3.y * 64 + lane];
        float4 a00 = *(const float4*)(ea + (size_t)p0.x * 8);
        float4 a01 = *(const float4*)(ea + (size_t)p0.x * 8 + 4);
        float4 a10 = *(const float4*)(ea + (size_t)p1.x * 8);
        float4 a11 = *(const float4*)(ea + (size_t)p1.x * 8 + 4);
        float4 a20 = *(const float4*)(ea + (size_t)p2.x * 8);
        float4 a21 = *(const float4*)(ea + (size_t)p2.x * 8 + 4);
        float4 a30 = *(const float4*)(ea + (size_t)p3.x * 8);
        float4 a31 = *(const float4*)(ea + (size_t)p3.x * 8 + 4);
        y[0] += a00.x * x0 + a10.x * x1 + a20.x * x2 + a30.x * x3;
        y[1] += a00.y * x0 + a10.y * x1 + a20.y * x2 + a30.y * x3;
        y[2] += a00.z * x0 + a10.z * x1 + a20.z * x2 + a30.z * x3;
        y[3] += a00.w * x0 + a10.w * x1 + a20.w * x2 + a30.w * x3;
        y[4] += a01.x * x0 + a11.x * x1 + a21.x * x2 + a31.x * x3;
        y[5] += a01.y * x0 + a11.y * x1 + a21.y * x2 + a31.y * x3;
        y[6] += a01.z * x0 + a11.z * x1 + a21.z * x2 + a31.z * x3;
        y[7] += a01.w * x0 + a11.w * x1 + a21.w * x2 + a31.w * x3;
        y[8] += x0 + x1 + x2 + x3;
    }
    for (; idx < rp1; idx++) {
        int2 p = cs2[idx];
        float xv = x[(size_t)p.y * 64 + lane];
        float4 a0 = *(const float4*)(ea + (size_t)p.x * 8);
        float4 a1 = *(const float4*)(ea + (size_t)p.x * 8 + 4);
        y[0] += a0.x * xv; y[1] += a0.y * xv; y[2] += a0.z * xv; y[3] += a0.w * xv;
        y[4] += a1.x * xv; y[5] += a1.y * xv; y[6] += a1.z * xv; y[7] += a1.w * xv;
        y[8] += xv;
    }
    float* zr = Z1 + (size_t)d * 640;
#pragma unroll
    for (int f = 0; f < 9; f++) zr[f * 64 + lane] = y[f];
    zr[576 + lane] = x[(size_t)d * 64 + lane];
}

// ---------------------------------------------------------------------------
// k_t: transpose [8192][C] -> [C][8192], 64n x 32c tiles, full-line coalesced
// on both sides. grid (128, C/32).
// ---------------------------------------------------------------------------
__global__ __launch_bounds__(256) void k_t(const float* __restrict__ src,
                                           float* __restrict__ dst, int C) {
    __shared__ float tl[64][33];
    const int n0 = blockIdx.x * 64;
    const int c0 = blockIdx.y * 32;
    const int t = threadIdx.x;
    {
        const int r = t >> 2, cq = (t & 3) * 8;
        const float4* sp = (const float4*)(src + (size_t)(n0 + r) * C + c0 + cq);
        float4 v0 = sp[0], v1 = sp[1];
        tl[r][cq + 0] = v0.x; tl[r][cq + 1] = v0.y; tl[r][cq + 2] = v0.z; tl[r][cq + 3] = v0.w;
        tl[r][cq + 4] = v1.x; tl[r][cq + 5] = v1.y; tl[r][cq + 6] = v1.z; tl[r][cq + 7] = v1.w;
    }
    __syncthreads();
    {
        const int cl = t >> 3, nq = (t & 7) * 8;
        float4 o0, o1;
        o0.x = tl[nq + 0][cl]; o0.y = tl[nq + 1][cl]; o0.z = tl[nq + 2][cl]; o0.w = tl[nq + 3][cl];
        o1.x = tl[nq + 4][cl]; o1.y = tl[nq + 5][cl]; o1.z = tl[nq + 6][cl]; o1.w = tl[nq + 7][cl];
        float4* dp = (float4*)(dst + (size_t)(c0 + cl) * 8192 + n0 + nq);
        dp[0] = o0; dp[1] = o1;
    }
}

// ---------------------------------------------------------------------------
// k_g1: h1 = relu(Z1t^T(k-major) @ Wf1 + bias1). lane = node, W on the
// SCALAR pipe (indices have no threadIdx -> s_load), z coalesced global b32.
// Block: 256 thr = 4 waves = 4 K-slices of 160; grid 256 = 128 n-grp x 2
// c-halves (24 cols each). LDS reduce over the 4 partials. 1 block/CU.
// ---------------------------------------------------------------------------
__global__ __launch_bounds__(256) void k_g1(const float* __restrict__ Z1t,
                                            const float* __restrict__ Wf1,
                                            const float* __restrict__ bias1,
                                            float* __restrict__ h1) {
    __shared__ float part[4][64][24];
    const int t = threadIdx.x;
    const int wv = t >> 6, lane = t & 63;
    const int ch = blockIdx.x & 1;        // col half: 0 -> cols 0..23, 1 -> 24..47
    const int n0 = (blockIdx.x >> 1) * 64;
    const float* zp = Z1t + (size_t)(wv * 160) * 8192 + n0 + lane;
    const float* wp = Wf1 + (size_t)(wv * 160) * 48 + ch * 24;
    float acc[24];
#pragma unroll
    for (int j = 0; j < 24; j++) acc[j] = 0.f;
#pragma unroll 2
    for (int k = 0; k < 160; k++) {
        float zv = zp[(size_t)k * 8192];
#pragma unroll
        for (int j = 0; j < 24; j++) acc[j] += wp[(size_t)k * 48 + j] * zv;
    }
#pragma unroll
    for (int j = 0; j < 24; j++) part[wv][lane][j] = acc[j];
    __syncthreads();
    for (int i = t; i < 64 * 24; i += 256) {
        int n = i / 24, j = i - n * 24;
        float v = part[0][n][j] + part[1][n][j] + part[2][n][j] + part[3][n][j]
                + bias1[ch * 24 + j];
        h1[(size_t)(n0 + n) * 48 + ch * 24 + j] = fmaxf(v, 0.f);
    }
}

// ---------------------------------------------------------------------------
// k_y2: one wave per dst, lanes 0..47 = h1 channel, unrolled-by-4.
// Z2 row = [y0..y8 (432), h1_d (48)].
// ---------------------------------------------------------------------------
__global__ __launch_bounds__(256) void k_y2(const int2* __restrict__ cs2,
                                            const float* __restrict__ ea,
                                            const float* __restrict__ h1,
                                            const int* __restrict__ row_ptr,
                                            float* __restrict__ Z2) {
    const int lane = threadIdx.x & 63;
    const int d = blockIdx.x * 4 + (threadIdx.x >> 6);
    if (lane >= 48) return;
    float y[9];
#pragma unroll
    for (int f = 0; f < 9; f++) y[f] = 0.f;
    const int rp0 = row_ptr[d], rp1 = row_ptr[d + 1];
    int idx = rp0;
    for (; idx + 4 <= rp1; idx += 4) {
        int2 p0 = cs2[idx], p1 = cs2[idx + 1], p2 = cs2[idx + 2], p3 = cs2[idx + 3];
        float x0 = h1[(size_t)p0.y * 48 + lane];
        float x1 = h1[(size_t)p1.y * 48 + lane];
        float x2 = h1[(size_t)p2.y * 48 + lane];
        float x3 = h1[(size_t)p3.y * 48 + lane];
        float4 a00 = *(const float4*)(ea + (size_t)p0.x * 8);
        float4 a01 = *(const float4*)(ea + (size_t)p0.x * 8 + 4);
        float4 a10 = *(const float4*)(ea + (size_t)p1.x * 8);
        float4 a11 = *(const float4*)(ea + (size_t)p1.x * 8 + 4);
        float4 a20 = *(const float4*)(ea + (size_t)p2.x * 8);
        float4 a21 = *(const float4*)(ea + (size_t)p2.x * 8 + 4);
        float4 a30 = *(const float4*)(ea + (size_t)p3.x * 8);
        float4 a31 = *(const float4*)(ea + (size_t)p3.x * 8 + 4);
        y[0] += a00.x * x0 + a10.x * x1 + a20.x * x2 + a30.x * x3;
        y[1] += a00.y * x0 + a10.y * x1 + a20.y * x2 + a30.y * x3;
        y[2] += a00.z * x0 + a10.z * x1 + a20.z * x2 + a30.z * x3;
        y[3] += a00.w * x0 + a10.w * x1 + a20.w * x2 + a30.w * x3;
        y[4] += a01.x * x0 + a11.x * x1 + a21.x * x2 + a31.x * x3;
        y[5] += a01.y * x0 + a11.y * x1 + a21.y * x2 + a31.y * x3;
        y[6] += a01.z * x0 + a11.z * x1 + a21.z * x2 + a31.z * x3;
        y[7] += a01.w * x0 + a11.w * x1 + a21.w * x2 + a31.w * x3;
        y[8] += x0 + x1 + x2 + x3;
    }
    for (; idx < rp1; idx++) {
        int2 p = cs2[idx];
        float xv = h1[(size_t)p.y * 48 + lane];
        float4 a0 = *(const float4*)(ea + (size_t)p.x * 8);
        float4 a1 = *(const float4*)(ea + (size_t)p.x * 8 + 4);
        y[0] += a0.x * xv; y[1] += a0.y * xv; y[2] += a0.z * xv; y[3] += a0.w * xv;
        y[4] += a1.x * xv; y[5] += a1.y * xv; y[6] += a1.z * xv; y[7] += a1.w * xv;
        y[8] += xv;
    }
    float* zr = Z2 + (size_t)d * 480;
#pragma unroll
    for (int f = 0; f < 9; f++) zr[f * 48 + lane] = y[f];
    zr[432 + lane] = h1[(size_t)d * 48 + lane];
}

// ---------------------------------------------------------------------------
// k_g2: h2 = relu(Z2t(k-major) @ Wf2 + bias2). Same structure as k_g1:
// 4 waves = 4 K-slices of 120; 2 col-halves of 16; 256 blocks.
// ---------------------------------------------------------------------------
__global__ __launch_bounds__(256) void k_g2(const float* __restrict__ Z2t,
                                            const float* __restrict__ Wf2,
                                            const float* __restrict__ bias2,
                                            float* __restrict__ h2) {
    __shared__ float part[4][64][16];
    const int t = threadIdx.x;
    const int wv = t >> 6, lane = t & 63;
    const int ch = blockIdx.x & 1;        // cols 0..15 / 16..31
    const int n0 = (blockIdx.x >> 1) * 64;
    const float* zp = Z2t + (size_t)(wv * 120) * 8192 + n0 + lane;
    const float* wp = Wf2 + (size_t)(wv * 120) * 32 + ch * 16;
    float acc[16];
#pragma unroll
    for (int j = 0; j < 16; j++) acc[j] = 0.f;
#pragma unroll 2
    for (int k = 0; k < 120; k++) {
        float zv = zp[(size_t)k * 8192];
#pragma unroll
        for (int j = 0; j < 16; j++) acc[j] += wp[(size_t)k * 32 + j] * zv;
    }
#pragma unroll
    for (int j = 0; j < 16; j++) part[wv][lane][j] = acc[j];
    __syncthreads();
    for (int i = t; i < 64 * 16; i += 256) {
        int n = i >> 4, j = i & 15;
        float v = part[0][n][j] + part[1][n][j] + part[2][n][j] + part[3][n][j]
                + bias2[ch * 16 + j];
        h2[(size_t)(n0 + n) * 32 + ch * 16 + j] = fmaxf(v, 0.f);
    }
}

// ---------------------------------------------------------------------------
// k_head: thread = (node, out-quad of 8): 16 mu + 16 ls outputs.
// hcat[d] = head(h2[d]) * dinv[d]; out init = self-loop + bias; dinv stored.
// ---------------------------------------------------------------------------
__global__ __launch_bounds__(256) void k_head(const float* __restrict__ h2,
                                              const float* __restrict__ mu_w,
                                              const float* __restrict__ mu_b,
                                              const float* __restrict__ ls_w,
                                              const float* __restrict__ ls_b,
                                              const int* __restrict__ row_ptr,
                                              float* __restrict__ hcat,
                                              float* __restrict__ dinv,
                                              float* __restrict__ out) {
    const int gid = blockIdx.x * 256 + threadIdx.x;
    const int n = gid >> 3, oq = gid & 7;
    const int q = oq >> 2;          // 0 = mu, 1 = ls
    const int j0 = (oq & 3) * 4;    // output col base
    const float* wh = (q ? ls_w : mu_w) + j0;
    const float* bh = q ? ls_b : mu_b;
    const float* hr = h2 + (size_t)n * 32;
    float4 acc = make_float4(0.f, 0.f, 0.f, 0.f);
#pragma unroll
    for (int i4 = 0; i4 < 8; i4++) {
        float4 v = *(const float4*)(hr + i4 * 4);
        float4 w0 = *(const float4*)(wh + (size_t)(i4 * 4 + 0) * 16);
        float4 w1 = *(const float4*)(wh + (size_t)(i4 * 4 + 1) * 16);
        float4 w2 = *(const float4*)(wh + (size_t)(i4 * 4 + 2) * 16);
        float4 w3 = *(const float4*)(wh + (size_t)(i4 * 4 + 3) * 16);
        acc.x += v.x * w0.x + v.y * w1.x + v.z * w2.x + v.w * w3.x;
        acc.y += v.x * w0.y + v.y * w1.y + v.z * w2.y + v.w * w3.y;
        acc.z += v.x * w0.z + v.y * w1.z + v.z * w2.z + v.w * w3.z;
        acc.w += v.x * w0.w + v.y * w1.w + v.z * w2.w + v.w * w3.w;
    }
    const int deg = row_ptr[n + 1] - row_ptr[n] + 1;
    const float invd = 1.f / (float)deg;
    const float di = rsqrtf((float)deg);
    if (oq == 0) dinv[n] = di;
    float4 hv, ov;
    hv.x = acc.x * di; hv.y = acc.y * di; hv.z = acc.z * di; hv.w = acc.w * di;
    float4 b = *(const float4*)(bh + j0);
    ov.x = acc.x * invd + b.x; ov.y = acc.y * invd + b.y;
    ov.z = acc.z * invd + b.z; ov.w = acc.w * invd + b.w;
    *(float4*)(hcat + (size_t)n * 32 + q * 16 + j0) = hv;
    *(float4*)(out + (q ? (size_t)NN * 16 : (size_t)0) + (size_t)n * 16 + j0) = ov;
}

// ---------------------------------------------------------------------------
// k_gcn: half-wave (32 lanes) per dst: out[d] += dinv[d] * sum_s hcat[s]
// (hcat pre-scaled by dinv[s]). Unrolled by 4.
// ---------------------------------------------------------------------------
__global__ __launch_bounds__(256) void k_gcn(const int2* __restrict__ cs2,
                                             const int* __restrict__ row_ptr,
                                             const float* __restrict__ hcat,
                                             const float* __restrict__ dinv,
                                             float* __restrict__ out) {
    const int t = threadIdx.x;
    const int lane32 = t & 31;
    const int d = blockIdx.x * 8 + (t >> 5);
    float acc = 0.f;
    const int rp0 = row_ptr[d], rp1 = row_ptr[d + 1];
    int idx = rp0;
    for (; idx + 4 <= rp1; idx += 4) {
        int2 p0 = cs2[idx], p1 = cs2[idx + 1], p2 = cs2[idx + 2], p3 = cs2[idx + 3];
        float v0 = hcat[(size_t)p0.y * 32 + lane32];
        float v1 = hcat[(size_t)p1.y * 32 + lane32];
        float v2 = hcat[(size_t)p2.y * 32 + lane32];
        float v3 = hcat[(size_t)p3.y * 32 + lane32];
        acc += (v0 + v1) + (v2 + v3);
    }
    for (; idx < rp1; idx++) {
        int2 p = cs2[idx];
        acc += hcat[(size_t)p.y * 32 + lane32];
    }
    acc *= dinv[d];
    const int col = lane32 & 15;
    const size_t addr = (lane32 < 16) ? ((size_t)d * 16 + col)
                                      : ((size_t)NN * 16 + (size_t)d * 16 + col);
    out[addr] += acc;
}

extern "C" void kernel_launch(void* const* d_in, const int* in_sizes, int n_in,
                              void* d_out, int out_size, void* d_ws, size_t ws_size,
                              hipStream_t stream) {
    const float* x     = (const float*)d_in[0];
    const int*   ei    = (const int*)d_in[1];
    const float* ea    = (const float*)d_in[2];
    const float* nn1_w = (const float*)d_in[3];
    const float* nn1_b = (const float*)d_in[4];
    const float* root1 = (const float*)d_in[5];
    const float* bias1 = (const float*)d_in[6];
    const float* nn2_w = (const float*)d_in[7];
    const float* nn2_b = (const float*)d_in[8];
    const float* root2 = (const float*)d_in[9];
    const float* bias2 = (const float*)d_in[10];
    const float* mu_w  = (const float*)d_in[11];
    const float* mu_b  = (const float*)d_in[12];
    const float* ls_w  = (const float*)d_in[13];
    const float* ls_b  = (const float*)d_in[14];
    float* out = (float*)d_out;

    // Workspace (float units, all 16B-aligned starts)
    float* W       = (float*)d_ws;
    float* Wf1     = W;                        //    30,720
    float* Wf2     = Wf1 + 30720;              //    15,360
    int*   cnt     = (int*)(Wf2 + 15360);      //     8,192
    int*   row_ptr = cnt + 8192;               //     8,196
    int*   cursor  = row_ptr + 8196;           //     8,192
    int2*  cs2     = (int2*)(cursor + 8192);   //    65,536 int2
    float* Z1      = (float*)(cs2 + 65536);    // 5,242,880
    float* Z1t     = Z1 + 5242880;             // 5,242,880
    float* Z2      = Z1t + 5242880;            // 3,932,160
    float* Z2t     = Z2 + 3932160;             // 3,932,160
    float* h1      = Z2t + 3932160;            //   393,216
    float* h2      = h1 + 393216;              //   262,144
    float* hcat    = h2 + 262144;              //   262,144
    float* dinv    = hcat + 262144;            //     8,192
    // total ~78 MB

    hipMemsetAsync(cnt, 0, 8192 * sizeof(int), stream);
    k_hist<<<dim3(256), dim3(256), 0, stream>>>(ei, cnt);
    k_scan<<<dim3(1), dim3(1024), 0, stream>>>(cnt, row_ptr, cursor);
    k_scatpack<<<dim3(436), dim3(256), 0, stream>>>(ei, cursor, cs2,
                                                    nn1_w, nn1_b, root1,
                                                    nn2_w, nn2_b, root2, Wf1, Wf2);
    k_y1<<<dim3(2048), dim3(256), 0, stream>>>(cs2, ea, x, row_ptr, Z1);
    k_t<<<dim3(128, 20), dim3(256), 0, stream>>>(Z1, Z1t, 640);
    k_g1<<<dim3(256), dim3(256), 0, stream>>>(Z1t, Wf1, bias1, h1);
    k_y2<<<dim3(2048), dim3(256), 0, stream>>>(cs2, ea, h1, row_ptr, Z2);
    k_t<<<dim3(128, 15), dim3(256), 0, stream>>>(Z2, Z2t, 480);
    k_g2<<<dim3(256), dim3(256), 0, stream>>>(Z2t, Wf2, bias2, h2);
    k_head<<<dim3(256), dim3(256), 0, stream>>>(h2, mu_w, mu_b, ls_w, ls_b,
                                                row_ptr, hcat, dinv, out);
    k_gcn<<<dim3(1024), dim3(256), 0, stream>>>(cs2, row_ptr, hcat, dinv, out);
}